// Round 1
// baseline (260.208 us; speedup 1.0000x reference)
//
#include <hip/hip_runtime.h>

#define N_NODES 100000
#define N_EDGES 1600000
#define D_IN 32
#define D_HID 16
#define D_OUT 2

// ---------------------------------------------------------------------------
// Kernel 1: per-node dense transforms for layer 1.
//   xr[i]  = x[i] @ w1_rel^T            (aggregated over edges later)
//   agg[i] = x[i] @ w1_root^T + b1      (accumulator pre-initialized with root term)
// ---------------------------------------------------------------------------
__global__ __launch_bounds__(256) void k_node1(
    const float* __restrict__ x,
    const float* __restrict__ w_rel,    // [D_HID, D_IN]
    const float* __restrict__ w_root,   // [D_HID, D_IN]
    const float* __restrict__ b,        // [D_HID]
    float* __restrict__ xr,             // [N, D_HID]
    float* __restrict__ agg)            // [N, D_HID]
{
    __shared__ float s_rel[D_HID * D_IN];
    __shared__ float s_root[D_HID * D_IN];
    __shared__ float s_b[D_HID];
    for (int i = threadIdx.x; i < D_HID * D_IN; i += blockDim.x) {
        s_rel[i]  = w_rel[i];
        s_root[i] = w_root[i];
    }
    if (threadIdx.x < D_HID) s_b[threadIdx.x] = b[threadIdx.x];
    __syncthreads();

    int node = blockIdx.x * blockDim.x + threadIdx.x;
    if (node >= N_NODES) return;

    float row[D_IN];
    const float4* xp = (const float4*)(x + (size_t)node * D_IN);
#pragma unroll
    for (int i = 0; i < D_IN / 4; i++) {
        float4 v = xp[i];
        row[4*i+0] = v.x; row[4*i+1] = v.y; row[4*i+2] = v.z; row[4*i+3] = v.w;
    }

    float oa[D_HID], orr[D_HID];
#pragma unroll
    for (int o = 0; o < D_HID; o++) {
        float a = 0.f, r = s_b[o];
#pragma unroll
        for (int k = 0; k < D_IN; k++) {
            a += row[k] * s_rel[o * D_IN + k];
            r += row[k] * s_root[o * D_IN + k];
        }
        oa[o] = a; orr[o] = r;
    }

    float4* xrp  = (float4*)(xr  + (size_t)node * D_HID);
    float4* aggp = (float4*)(agg + (size_t)node * D_HID);
#pragma unroll
    for (int i = 0; i < D_HID / 4; i++) {
        xrp[i]  = make_float4(oa[4*i], oa[4*i+1], oa[4*i+2], oa[4*i+3]);
        aggp[i] = make_float4(orr[4*i], orr[4*i+1], orr[4*i+2], orr[4*i+3]);
    }
}

// ---------------------------------------------------------------------------
// Kernel 2: layer-1 scatter-add. 16 threads per edge (one per hidden feature).
//   agg[dst][f] += xr[src][f]
// ---------------------------------------------------------------------------
__global__ __launch_bounds__(256) void k_scatter1(
    const int* __restrict__ ei,         // [2, E]
    const float* __restrict__ xr,       // [N, D_HID]
    float* __restrict__ agg)            // [N, D_HID]
{
    int tid = blockIdx.x * blockDim.x + threadIdx.x;
    if (tid >= N_EDGES * D_HID) return;
    int e = tid >> 4;
    int f = tid & (D_HID - 1);
    int src = ei[e];
    int dst = ei[N_EDGES + e];
    float v = xr[src * D_HID + f];
    atomicAdd(&agg[dst * D_HID + f], v);
}

// ---------------------------------------------------------------------------
// Kernel 3: relu + per-node dense transforms for layer 2.
//   h      = relu(agg1)                 (kept in registers only)
//   hr[i]  = h @ w2_rel^T               (aggregated over edges later)
//   out[i] = h @ w2_root^T + b2         (output pre-initialized with root term)
// ---------------------------------------------------------------------------
__global__ __launch_bounds__(256) void k_node2(
    const float* __restrict__ agg,      // [N, D_HID]
    const float* __restrict__ w_rel,    // [D_OUT, D_HID]
    const float* __restrict__ w_root,   // [D_OUT, D_HID]
    const float* __restrict__ b,        // [D_OUT]
    float* __restrict__ hr,             // [N, D_OUT]
    float* __restrict__ outv)           // [N, D_OUT]
{
    __shared__ float s_rel[D_OUT * D_HID];
    __shared__ float s_root[D_OUT * D_HID];
    __shared__ float s_b[D_OUT];
    for (int i = threadIdx.x; i < D_OUT * D_HID; i += blockDim.x) {
        s_rel[i]  = w_rel[i];
        s_root[i] = w_root[i];
    }
    if (threadIdx.x < D_OUT) s_b[threadIdx.x] = b[threadIdx.x];
    __syncthreads();

    int node = blockIdx.x * blockDim.x + threadIdx.x;
    if (node >= N_NODES) return;

    float h[D_HID];
    const float4* ap = (const float4*)(agg + (size_t)node * D_HID);
#pragma unroll
    for (int i = 0; i < D_HID / 4; i++) {
        float4 v = ap[i];
        h[4*i+0] = fmaxf(v.x, 0.f); h[4*i+1] = fmaxf(v.y, 0.f);
        h[4*i+2] = fmaxf(v.z, 0.f); h[4*i+3] = fmaxf(v.w, 0.f);
    }

    float o_rel[D_OUT], o_root[D_OUT];
#pragma unroll
    for (int o = 0; o < D_OUT; o++) {
        float a = 0.f, r = s_b[o];
#pragma unroll
        for (int k = 0; k < D_HID; k++) {
            a += h[k] * s_rel[o * D_HID + k];
            r += h[k] * s_root[o * D_HID + k];
        }
        o_rel[o] = a; o_root[o] = r;
    }

    ((float2*)(hr   + (size_t)node * D_OUT))[0] = make_float2(o_rel[0], o_rel[1]);
    ((float2*)(outv + (size_t)node * D_OUT))[0] = make_float2(o_root[0], o_root[1]);
}

// ---------------------------------------------------------------------------
// Kernel 4: layer-2 scatter-add. 2 threads per edge.
//   out[dst][f] += hr[src][f]
// ---------------------------------------------------------------------------
__global__ __launch_bounds__(256) void k_scatter2(
    const int* __restrict__ ei,
    const float* __restrict__ hr,       // [N, D_OUT]
    float* __restrict__ outv)           // [N, D_OUT]
{
    int tid = blockIdx.x * blockDim.x + threadIdx.x;
    if (tid >= N_EDGES * D_OUT) return;
    int e = tid >> 1;
    int f = tid & (D_OUT - 1);
    int src = ei[e];
    int dst = ei[N_EDGES + e];
    float v = hr[src * D_OUT + f];
    atomicAdd(&outv[dst * D_OUT + f], v);
}

extern "C" void kernel_launch(void* const* d_in, const int* in_sizes, int n_in,
                              void* d_out, int out_size, void* d_ws, size_t ws_size,
                              hipStream_t stream) {
    const float* x       = (const float*)d_in[0];
    const int*   ei      = (const int*)  d_in[1];
    const float* w1_rel  = (const float*)d_in[2];
    const float* w1_root = (const float*)d_in[3];
    const float* b1      = (const float*)d_in[4];
    const float* w2_rel  = (const float*)d_in[5];
    const float* w2_root = (const float*)d_in[6];
    const float* b2      = (const float*)d_in[7];
    float* out = (float*)d_out;

    // Workspace layout (all re-written every call; no reliance on prior state):
    //   xr  : N * D_HID floats  (6.4 MB)
    //   agg : N * D_HID floats  (6.4 MB)
    //   hr  : N * D_OUT floats  (0.8 MB)
    float* xr  = (float*)d_ws;
    float* agg = xr  + (size_t)N_NODES * D_HID;
    float* hr  = agg + (size_t)N_NODES * D_HID;

    dim3 blk(256);

    k_node1<<<dim3((N_NODES + 255) / 256), blk, 0, stream>>>(
        x, w1_rel, w1_root, b1, xr, agg);

    k_scatter1<<<dim3((N_EDGES * D_HID + 255) / 256), blk, 0, stream>>>(
        ei, xr, agg);

    k_node2<<<dim3((N_NODES + 255) / 256), blk, 0, stream>>>(
        agg, w2_rel, w2_root, b2, hr, out);

    k_scatter2<<<dim3((N_EDGES * D_OUT + 255) / 256), blk, 0, stream>>>(
        ei, hr, out);
}